// Round 14
// baseline (834.148 us; speedup 1.0000x reference)
//
#include <hip/hip_runtime.h>
#include <hip/hip_bf16.h>

#define N_ATOMS   500000
#define N_BONDS   1000000
#define MAX_NB    6
#define ATOM_FDIM 133
#define BOND_FDIM 14
#define HIDDEN    128
#define N_MOLS    25000
#define APM       20

typedef __attribute__((ext_vector_type(8))) short short8;
typedef __attribute__((ext_vector_type(4))) float f32x4;
typedef unsigned short u16;
typedef unsigned int   u32;

__device__ __forceinline__ float bf2f(u16 u) {
    u32 t = ((u32)u) << 16;
    return __builtin_bit_cast(float, t);
}
__device__ __forceinline__ u16 f2bf(float f) {
    u32 t = __builtin_bit_cast(u32, f);
    t += 0x7FFFu + ((t >> 16) & 1u);
    return (u16)(t >> 16);
}
__device__ __forceinline__ u32 pk2(float a, float b) {
    return (u32)f2bf(a) | ((u32)f2bf(b) << 16);
}

// async global->LDS, 16B per lane. LDS dest = uniform base + lane*16; global src per-lane.
__device__ __forceinline__ void gl16(const u16* g, u16* l) {
    __builtin_amdgcn_global_load_lds(
        (__attribute__((address_space(1))) void*)(g),
        (__attribute__((address_space(3))) void*)(l), 16, 0, 0);
}

// ---------------- weight prep: fp32 -> padded bf16 ----------------
__global__ void prep_weights(const float* __restrict__ Wi, const float* __restrict__ Wh,
                             const float* __restrict__ Wo,
                             u16* __restrict__ Wip, u16* __restrict__ Whp, u16* __restrict__ Wop) {
    int stride = gridDim.x * blockDim.x;
    int tid = blockIdx.x * blockDim.x + threadIdx.x;
    for (int i = tid; i < 128 * 160; i += stride) {
        int r = i / 160, c = i % 160;
        Wip[i] = (c < 133) ? f2bf(Wi[r * 133 + c]) : (u16)0;
        Whp[i] = (c < 142) ? f2bf(Wh[r * 142 + c]) : (u16)0;
    }
    for (int i = tid; i < 128 * 288; i += stride) {
        int r = i / 288, c = i % 288;
        float v = 0.f;
        if (c < 133)      v = Wo[r * 261 + c];
        else if (c >= 160) v = Wo[r * 261 + (c - 27)];
        Wop[i] = f2bf(v);
    }
}

// ---------------- bond pre-sum: sum_j f_bonds[a2b[:,j]] -> bf16 [N][32] ----------------
__global__ __launch_bounds__(256) void bond_gather(const float* __restrict__ fb, const int* __restrict__ a2b,
                                                   u16* __restrict__ outp) {
    long t = (long)blockIdx.x * 256 + threadIdx.x;
    int atom = (int)(t >> 4);
    int c2   = (int)(t & 15);
    if (atom >= N_ATOMS) return;
    int c0 = 2 * c2, c1 = c0 + 1;
    float s0 = 0.f, s1 = 0.f;
    if (c0 < BOND_FDIM) {
#pragma unroll
        for (int j = 0; j < MAX_NB; j++) {
            int idx = a2b[atom * 6 + j];
            const float* row = fb + (long)idx * BOND_FDIM;
            s0 += row[c0];
            if (c1 < BOND_FDIM) s1 += row[c1];
        }
    }
    *(u32*)(outp + (long)atom * 32 + c0) = pk2(s0, s1);
}

// ---------------- gather-relu-sum: dst[a] = sum_j relu(src[a2a[a,j]]) (bf16 128-wide) ---
__global__ __launch_bounds__(256) void gather_relu_sum(const u16* __restrict__ src,
                                                       const int* __restrict__ a2a,
                                                       u16* __restrict__ dst) {
    long t = (long)blockIdx.x * 256 + threadIdx.x;
    int atom = (int)(t >> 4);
    int c8   = (int)(t & 15) << 3;
    float s[8] = {0, 0, 0, 0, 0, 0, 0, 0};
#pragma unroll
    for (int j = 0; j < MAX_NB; j++) {
        int idx = a2a[atom * 6 + j];
        uint4 v = *(const uint4*)(src + (long)idx * 128 + c8);
        u32 w[4] = {v.x, v.y, v.z, v.w};
#pragma unroll
        for (int q = 0; q < 4; q++) {
            s[2 * q]     += fmaxf(__builtin_bit_cast(float, w[q] << 16), 0.f);
            s[2 * q + 1] += fmaxf(__builtin_bit_cast(float, w[q] & 0xFFFF0000u), 0.f);
        }
    }
    uint4 o;
    o.x = pk2(s[0], s[1]);
    o.y = pk2(s[2], s[3]);
    o.z = pk2(s[4], s[5]);
    o.w = pk2(s[6], s[7]);
    *(uint4*)(dst + (long)atom * 128 + c8) = o;
}

// ---------------- persistent DMA-pipelined GEMM with linear-store epilogue (r13) -------
#define ISSUE_SLOT(d, t)                                                              \
    do {                                                                              \
        long r_ = (t) * TILE + wave * 16 + lrow;                                      \
        if (r_ > N_ATOMS - 1) r_ = N_ATOMS - 1;                                       \
        u16* ab_ = AL + ((d) * WAVES + wave) * (KB0 * 512);                           \
        {                                                                             \
            const u16* p_ = A0 + r_ * (long)ldA0 + kg * 8;                            \
            _Pragma("unroll") for (int kb = 0; kb < KB0; kb++)                        \
                gl16(p_ + kb * 32, ab_ + kb * 512);                                   \
        }                                                                             \
        if constexpr (KB1 > 0) {                                                      \
            const u16* p_ = A1 + r_ * (long)ldA1 + kg * 8;                            \
            _Pragma("unroll") for (int kb = 0; kb < KB1; kb++)                        \
                a1v[d][kb] = *(const uint4*)(p_ + kb * 32);                           \
        }                                                                             \
        if constexpr (ADDX) {                                                         \
            _Pragma("unroll") for (int n = 0; n < 8; n++)                             \
                xv[d][n] = *(const uint2*)(Xadd + r_ * 128 + n * 16 + kg * 4);        \
        }                                                                             \
    } while (0)

template <int KB0, int KB1, bool ADDX, bool BIAS, int WAVES>
__global__ __launch_bounds__(WAVES * 64) void gemm_dma(
    const u16* __restrict__ A0, int ldA0,
    const u16* __restrict__ A1, int ldA1,
    const u16* __restrict__ Wp, const float* __restrict__ bias,
    const u16* __restrict__ Xadd, u16* __restrict__ Out) {
    constexpr int KB    = KB0 + KB1;
    constexpr int KP    = KB * 32;
    constexpr int TILE  = WAVES * 16;
    constexpr long NT   = (N_ATOMS + TILE - 1) / TILE;
    constexpr int WSLOTS = KB * 8;
    constexpr int DEPTH = 2;
    constexpr int NWAIT = KB0 + (KB1 > 0 ? KB1 : 0) + (ADDX ? 8 : 0) + 4;
    static_assert(NWAIT <= 63, "vmcnt range");
    __shared__ __align__(16) u16 lds[WSLOTS * 512 + DEPTH * WAVES * KB0 * 512 + WAVES * 2048];

    const int lane = threadIdx.x & 63;
    const int wave = threadIdx.x >> 6;
    const int lrow = lane & 15;
    const int kg   = lane >> 4;

    u16* WL = lds;
    u16* AL = lds + WSLOTS * 512;
    u16* SB = lds + WSLOTS * 512 + DEPTH * WAVES * KB0 * 512;

    for (int s = wave; s < WSLOTS; s += WAVES) {
        int kb = s >> 3, n = s & 7;
        gl16(Wp + (n * 16 + lrow) * KP + kb * 32 + kg * 8, WL + s * 512);
    }
    asm volatile("s_waitcnt vmcnt(0)" ::: "memory");
    __syncthreads();

    float4 b4[8];
#pragma unroll
    for (int n = 0; n < 8; n++)
        b4[n] = BIAS ? *(const float4*)(bias + n * 16 + kg * 4) : (float4){0.f, 0.f, 0.f, 0.f};

    const int G  = gridDim.x;
    const long t0 = blockIdx.x;

    uint4 a1v[DEPTH][KB1 > 0 ? KB1 : 1];
    uint2 xv[DEPTH][ADDX ? 8 : 1];

#pragma unroll
    for (int d = 0; d < DEPTH; d++) ISSUE_SLOT(d, t0 + (long)d * G);
    __builtin_amdgcn_sched_barrier(0);

#pragma unroll 1
    for (long tt = t0; tt < NT; tt += (long)DEPTH * G) {
#pragma unroll
        for (int d = 0; d < DEPTH; d++) {
            long t = tt + (long)d * G;
            if (t < NT) {
                asm volatile("s_waitcnt vmcnt(%0)" :: "n"(NWAIT) : "memory");
                __builtin_amdgcn_sched_barrier(0);

                const u16* ab = AL + (d * WAVES + wave) * (KB0 * 512);
                f32x4 acc[8];
#pragma unroll
                for (int n = 0; n < 8; n++) acc[n] = (f32x4){0.f, 0.f, 0.f, 0.f};
#pragma unroll
                for (int kb = 0; kb < KB; kb++) {
                    short8 af;
                    if (kb < KB0) af = *(const short8*)(ab + kb * 512 + lane * 8);
                    else          af = __builtin_bit_cast(short8, a1v[d][(kb - KB0) < KB1 ? (kb - KB0) : 0]);
#pragma unroll
                    for (int n = 0; n < 8; n++) {
                        short8 bf = *(const short8*)(WL + (kb * 8 + n) * 512 + lane * 8);
                        acc[n] = __builtin_amdgcn_mfma_f32_16x16x32_bf16(bf, af, acc[n], 0, 0, 0);
                    }
                }

                const long wrow0 = t * TILE + wave * 16;
                if (wrow0 < N_ATOMS) {
                    u16* sb = SB + wave * 2048;
#pragma unroll
                    for (int n = 0; n < 8; n++) {
                        float v0 = acc[n][0] + b4[n].x;
                        float v1 = acc[n][1] + b4[n].y;
                        float v2 = acc[n][2] + b4[n].z;
                        float v3 = acc[n][3] + b4[n].w;
                        if constexpr (ADDX) {
                            v0 += __builtin_bit_cast(float, xv[d][n].x << 16);
                            v1 += __builtin_bit_cast(float, xv[d][n].x & 0xFFFF0000u);
                            v2 += __builtin_bit_cast(float, xv[d][n].y << 16);
                            v3 += __builtin_bit_cast(float, xv[d][n].y & 0xFFFF0000u);
                        }
                        uint2 o;
                        o.x = pk2(v0, v1);
                        o.y = pk2(v2, v3);
                        int sboff = lrow * 256 + ((n * 32 + kg * 8) ^ ((lrow & 7) << 4));
                        *(uint2*)(sb + (sboff >> 1)) = o;
                    }
#pragma unroll
                    for (int i = 0; i < 4; i++) {
                        int R = i * 4 + (lane >> 4);
                        int B = ((lane & 15) * 16) ^ ((R & 7) << 4);
                        uint4 v = *(const uint4*)(sb + ((R * 256 + B) >> 1));
                        *(uint4*)(Out + wrow0 * 128 + i * 512 + lane * 8) = v;
                    }
                }
                __builtin_amdgcn_sched_barrier(0);
                ISSUE_SLOT(d, t + (long)DEPTH * G);
                __builtin_amdgcn_sched_barrier(0);
            }
        }
    }
}

// ---------------- fused Wo GEMM + per-molecule max-readout ----------------
// One wave = one molecule (20 rows): subtile0 = rows 0..15, subtile1 = rows 16..19
// (lanes 4..15 point at dup rows 16..19 -> max unaffected, L2 dedups reads).
// Epilogue: relu in f32, 16-lane shfl_xor max per column, dot with ffn_w, cross-kg
// sum, ONE 4-byte store per molecule. Replaces 128MB atom_hiddens write + 128MB
// readout read + readout dispatch.
__global__ __launch_bounds__(256) void gemm_wo_fused(
    const u16* __restrict__ fa, const u16* __restrict__ nsum,
    const u16* __restrict__ Wp, const float* __restrict__ bias,
    const float* __restrict__ ffn_w, const float* __restrict__ ffn_b,
    float* __restrict__ out) {
    constexpr int KB0 = 5, KB1 = 4, KB = 9, KP = 288;
    constexpr int WAVES = 4, DEPTH = 2;
    constexpr int WSLOTS = KB * 8;              // 72 KB
    constexpr int NWAIT = 2 * KB0 + 2 * KB1 + 1;  // 10 DMA + 8 reg loads + 1 store = 19
    __shared__ __align__(16) u16 lds[WSLOTS * 512 + DEPTH * WAVES * 2 * KB0 * 512];  // 152 KB

    const int lane = threadIdx.x & 63;
    const int wave = threadIdx.x >> 6;
    const int lrow = lane & 15;
    const int kg   = lane >> 4;

    u16* WL = lds;
    u16* AL = lds + WSLOTS * 512;

    for (int s = wave; s < WSLOTS; s += WAVES) {
        int kb = s >> 3, n = s & 7;
        gl16(Wp + (n * 16 + lrow) * KP + kb * 32 + kg * 8, WL + s * 512);
    }
    asm volatile("s_waitcnt vmcnt(0)" ::: "memory");
    __syncthreads();

    f32x4 bb[8], fw[8];
#pragma unroll
    for (int n = 0; n < 8; n++) {
        bb[n] = __builtin_bit_cast(f32x4, *(const float4*)(bias + n * 16 + kg * 4));
        fw[n] = __builtin_bit_cast(f32x4, *(const float4*)(ffn_w + n * 16 + kg * 4));
    }
    const float fb0 = ffn_b[0];

    const long TOTW = (long)gridDim.x * WAVES;
    const long w0   = (long)blockIdx.x * WAVES + wave;

    uint4 a1v[DEPTH][2][KB1];

    auto issue = [&](int d, long m) {
        long mm = (m < N_MOLS) ? m : (N_MOLS - 1);
        long base = mm * APM;
        long r0 = base + lrow;
        long r1 = base + 16 + (lrow & 3);
        u16* ab = AL + ((d * WAVES + wave) * (2 * KB0)) * 512;
        const u16* p0 = fa + r0 * 160 + kg * 8;
#pragma unroll
        for (int kb = 0; kb < KB0; kb++) gl16(p0 + kb * 32, ab + kb * 512);
        const u16* p1 = fa + r1 * 160 + kg * 8;
#pragma unroll
        for (int kb = 0; kb < KB0; kb++) gl16(p1 + kb * 32, ab + (KB0 + kb) * 512);
        const u16* q0 = nsum + r0 * 128 + kg * 8;
#pragma unroll
        for (int kb = 0; kb < KB1; kb++) a1v[d][0][kb] = *(const uint4*)(q0 + kb * 32);
        const u16* q1 = nsum + r1 * 128 + kg * 8;
#pragma unroll
        for (int kb = 0; kb < KB1; kb++) a1v[d][1][kb] = *(const uint4*)(q1 + kb * 32);
    };

#pragma unroll
    for (int d = 0; d < DEPTH; d++) issue(d, w0 + (long)d * TOTW);
    __builtin_amdgcn_sched_barrier(0);

#pragma unroll 1
    for (long mm0 = w0; mm0 < N_MOLS; mm0 += (long)DEPTH * TOTW) {
#pragma unroll
        for (int d = 0; d < DEPTH; d++) {
            long m = mm0 + (long)d * TOTW;
            if (m < N_MOLS) {
                asm volatile("s_waitcnt vmcnt(%0)" :: "n"(NWAIT) : "memory");
                __builtin_amdgcn_sched_barrier(0);

                const u16* ab = AL + ((d * WAVES + wave) * (2 * KB0)) * 512;
                f32x4 acc0[8], acc1[8];
#pragma unroll
                for (int n = 0; n < 8; n++) {
                    acc0[n] = (f32x4){0.f, 0.f, 0.f, 0.f};
                    acc1[n] = (f32x4){0.f, 0.f, 0.f, 0.f};
                }
#pragma unroll
                for (int kb = 0; kb < KB; kb++) {
                    short8 af0, af1;
                    if (kb < KB0) {
                        af0 = *(const short8*)(ab + kb * 512 + lane * 8);
                        af1 = *(const short8*)(ab + (KB0 + kb) * 512 + lane * 8);
                    } else {
                        af0 = __builtin_bit_cast(short8, a1v[d][0][(kb - KB0) < KB1 ? (kb - KB0) : 0]);
                        af1 = __builtin_bit_cast(short8, a1v[d][1][(kb - KB0) < KB1 ? (kb - KB0) : 0]);
                    }
#pragma unroll
                    for (int n = 0; n < 8; n++) {
                        short8 bf = *(const short8*)(WL + (kb * 8 + n) * 512 + lane * 8);
                        acc0[n] = __builtin_amdgcn_mfma_f32_16x16x32_bf16(bf, af0, acc0[n], 0, 0, 0);
                        acc1[n] = __builtin_amdgcn_mfma_f32_16x16x32_bf16(bf, af1, acc1[n], 0, 0, 0);
                    }
                }

                float part = 0.f;
#pragma unroll
                for (int n = 0; n < 8; n++) {
#pragma unroll
                    for (int j = 0; j < 4; j++) {
                        float w = fmaxf(acc0[n][j] + bb[n][j], 0.f);
                        w = fmaxf(w, fmaxf(acc1[n][j] + bb[n][j], 0.f));
#pragma unroll
                        for (int sft = 1; sft <= 8; sft <<= 1)
                            w = fmaxf(w, __shfl_xor(w, sft, 64));
                        part += w * fw[n][j];
                    }
                }
                part += __shfl_xor(part, 16, 64);
                part += __shfl_xor(part, 32, 64);
                if (lane == 0) out[m] = part + fb0;

                __builtin_amdgcn_sched_barrier(0);
                issue(d, m + (long)DEPTH * TOTW);
                __builtin_amdgcn_sched_barrier(0);
            }
        }
    }
    asm volatile("s_waitcnt vmcnt(0)" ::: "memory");
}

// ---------------- fused Wi GEMM + fa conversion (r9/r13 exact) ----------
__global__ __launch_bounds__(512, 2) void gemm_wi(
    const float* __restrict__ FA, const u16* __restrict__ Wp,
    const float* __restrict__ bias, u16* __restrict__ fa16, u16* __restrict__ Out) {
    constexpr int KB = 5, KP = 160, TILE = 128;
    constexpr long NT = (N_ATOMS + TILE - 1) / TILE;
    constexpr int WSLOTS = KB * 8;
    constexpr int DEPTH = 2;
    constexpr int NWAIT = 23;
    __shared__ __align__(16) u16 WL[WSLOTS * 512];

    const int lane = threadIdx.x & 63;
    const int wave = threadIdx.x >> 6;
    const int lrow = lane & 15;
    const int kg   = lane >> 4;

    for (int s = wave; s < WSLOTS; s += 8) {
        int kb = s >> 3, n = s & 7;
        gl16(Wp + (n * 16 + lrow) * KP + kb * 32 + kg * 8, WL + s * 512);
    }
    asm volatile("s_waitcnt vmcnt(0)" ::: "memory");
    __syncthreads();

    float4 b4[8];
#pragma unroll
    for (int n = 0; n < 8; n++) b4[n] = *(const float4*)(bias + n * 16 + kg * 4);

    const int G  = gridDim.x;
    const long t0 = blockIdx.x;

    uint4 af32[DEPTH][4][2];
    uint4 a4[DEPTH];
    float a4s[DEPTH];

#define WI_ISSUE(d, t)                                                         \
    do {                                                                       \
        long r_ = (t) * TILE + wave * 16 + lrow;                               \
        if (r_ > N_ATOMS - 1) r_ = N_ATOMS - 1;                                \
        const float* p_ = FA + r_ * (long)ATOM_FDIM + kg * 8;                  \
        _Pragma("unroll") for (int kb = 0; kb < 4; kb++) {                     \
            af32[d][kb][0] = *(const uint4*)(p_ + kb * 32);                    \
            af32[d][kb][1] = *(const uint4*)(p_ + kb * 32 + 4);                \
        }                                                                      \
        if (kg == 0) {                                                         \
            const float* q_ = FA + r_ * (long)ATOM_FDIM + 128;                 \
            a4[d]  = *(const uint4*)(q_);                                      \
            a4s[d] = q_[4];                                                    \
        }                                                                      \
    } while (0)

#pragma unroll
    for (int d = 0; d < DEPTH; d++) WI_ISSUE(d, t0 + (long)d * G);
    __builtin_amdgcn_sched_barrier(0);

#pragma unroll 1
    for (long tt = t0; tt < NT; tt += (long)DEPTH * G) {
#pragma unroll
        for (int d = 0; d < DEPTH; d++) {
            long t = tt + (long)d * G;
            if (t < NT) {
                asm volatile("s_waitcnt vmcnt(%0)" :: "n"(NWAIT) : "memory");
                __builtin_amdgcn_sched_barrier(0);

                long r = t * TILE + wave * 16 + lrow;
                bool wr = (r < N_ATOMS);

                short8 frag[5];
#pragma unroll
                for (int kb = 0; kb < 4; kb++) {
                    float4 lo = __builtin_bit_cast(float4, af32[d][kb][0]);
                    float4 hi = __builtin_bit_cast(float4, af32[d][kb][1]);
                    uint4 pk;
                    pk.x = pk2(lo.x, lo.y);
                    pk.y = pk2(lo.z, lo.w);
                    pk.z = pk2(hi.x, hi.y);
                    pk.w = pk2(hi.z, hi.w);
                    frag[kb] = __builtin_bit_cast(short8, pk);
                }
                {
                    uint4 pk = (uint4){0, 0, 0, 0};
                    if (kg == 0) {
                        float4 q = __builtin_bit_cast(float4, a4[d]);
                        pk.x = pk2(q.x, q.y);
                        pk.y = pk2(q.z, q.w);
                        pk.z = pk2(a4s[d], 0.f);
                    }
                    frag[4] = __builtin_bit_cast(short8, pk);
                }

                f32x4 acc[8];
#pragma unroll
                for (int n = 0; n < 8; n++) acc[n] = (f32x4){0.f, 0.f, 0.f, 0.f};
#pragma unroll
                for (int kb = 0; kb < 5; kb++) {
#pragma unroll
                    for (int n = 0; n < 8; n++) {
                        short8 bf = *(const short8*)(WL + (kb * 8 + n) * 512 + lane * 8);
                        acc[n] = __builtin_amdgcn_mfma_f32_16x16x32_bf16(bf, frag[kb], acc[n], 0, 0, 0);
                    }
                }

                if (wr) {
#pragma unroll
                    for (int kb = 0; kb < 5; kb++)
                        *(uint4*)(fa16 + r * 160 + kb * 32 + kg * 8) = __builtin_bit_cast(uint4, frag[kb]);
#pragma unroll
                    for (int n = 0; n < 8; n++) {
                        uint2 o;
                        o.x = pk2(acc[n][0] + b4[n].x, acc[n][1] + b4[n].y);
                        o.y = pk2(acc[n][2] + b4[n].z, acc[n][3] + b4[n].w);
                        *(uint2*)(Out + r * 128 + n * 16 + kg * 4) = o;
                    }
                }
                __builtin_amdgcn_sched_barrier(0);
                WI_ISSUE(d, t + (long)DEPTH * G);
                __builtin_amdgcn_sched_barrier(0);
            }
        }
    }
#undef WI_ISSUE
}

extern "C" void kernel_launch(void* const* d_in, const int* in_sizes, int n_in,
                              void* d_out, int out_size, void* d_ws, size_t ws_size,
                              hipStream_t stream) {
    const float* f_atoms = (const float*)d_in[0];
    const float* f_bonds = (const float*)d_in[1];
    const float* Wi_w = (const float*)d_in[2];
    const float* Wi_b = (const float*)d_in[3];
    const float* Wh_w = (const float*)d_in[4];
    const float* Wh_b = (const float*)d_in[5];
    const float* Wo_w = (const float*)d_in[6];
    const float* Wo_b = (const float*)d_in[7];
    const float* ffn_w = (const float*)d_in[8];
    const float* ffn_b = (const float*)d_in[9];
    const int* a2a = (const int*)d_in[10];
    const int* a2b = (const int*)d_in[11];
    float* out = (float*)d_out;

    char* ws = (char*)d_ws;
    u16* fa    = (u16*)(ws);                  // 160,000,000
    u16* xb    = (u16*)(ws + 160000000L);     // 128,000,000  (pre-relu x)
    u16* msgA  = (u16*)(ws + 288000000L);     // 128,000,000
    u16* msgB  = (u16*)(ws + 416000000L);     // 128,000,000
    u16* nsum  = (u16*)(ws + 544000000L);     // 128,000,000
    u16* nbond = (u16*)(ws + 672000000L);     // 32,000,000
    u16* Wip   = (u16*)(ws + 704000000L);     // 40960
    u16* Whp   = (u16*)(ws + 704040960L);     // 40960
    u16* Wop   = (u16*)(ws + 704081920L);     // 73728

    prep_weights<<<64, 256, 0, stream>>>(Wi_w, Wh_w, Wo_w, Wip, Whp, Wop);
    bond_gather<<<31250, 256, 0, stream>>>(f_bonds, a2b, nbond);

    // x = f_atoms @ Wi^T + b (pre-relu); also emits padded bf16 fa
    gemm_wi<<<256, 512, 0, stream>>>(f_atoms, Wip, Wi_b, fa, xb);

    // depth 1: A0=nsum (DMA), A1=nbond (reg), X=xb (reg)
    gather_relu_sum<<<31250, 256, 0, stream>>>(xb, a2a, nsum);
    gemm_dma<4, 1, true, true, 8><<<256, 512, 0, stream>>>(
        nsum, 128, nbond, 32, Whp, Wh_b, xb, msgA);
    // depth 2
    gather_relu_sum<<<31250, 256, 0, stream>>>(msgA, a2a, nsum);
    gemm_dma<4, 1, true, true, 8><<<256, 512, 0, stream>>>(
        nsum, 128, nbond, 32, Whp, Wh_b, xb, msgB);
    // final: fused Wo + per-molecule max readout (one wave = one molecule)
    gather_relu_sum<<<31250, 256, 0, stream>>>(msgB, a2a, nsum);
    gemm_wo_fused<<<256, 256, 0, stream>>>(fa, nsum, Wop, Wo_b, ffn_w, ffn_b, out);
}

// Round 15
// 820.203 us; speedup vs baseline: 1.0170x; 1.0170x over previous
//
#include <hip/hip_runtime.h>
#include <hip/hip_bf16.h>

#define N_ATOMS   500000
#define N_BONDS   1000000
#define MAX_NB    6
#define ATOM_FDIM 133
#define BOND_FDIM 14
#define HIDDEN    128
#define N_MOLS    25000
#define APM       20

typedef __attribute__((ext_vector_type(8))) short short8;
typedef __attribute__((ext_vector_type(4))) float f32x4;
typedef unsigned short u16;
typedef unsigned int   u32;

__device__ __forceinline__ float bf2f(u16 u) {
    u32 t = ((u32)u) << 16;
    return __builtin_bit_cast(float, t);
}
__device__ __forceinline__ u16 f2bf(float f) {
    u32 t = __builtin_bit_cast(u32, f);
    t += 0x7FFFu + ((t >> 16) & 1u);
    return (u16)(t >> 16);
}
__device__ __forceinline__ u32 pk2(float a, float b) {
    return (u32)f2bf(a) | ((u32)f2bf(b) << 16);
}

// async global->LDS, 16B per lane. LDS dest = uniform base + lane*16; global src per-lane.
__device__ __forceinline__ void gl16(const u16* g, u16* l) {
    __builtin_amdgcn_global_load_lds(
        (__attribute__((address_space(1))) void*)(g),
        (__attribute__((address_space(3))) void*)(l), 16, 0, 0);
}

// ---------------- weight prep: fp32 -> padded bf16 ----------------
__global__ void prep_weights(const float* __restrict__ Wi, const float* __restrict__ Wh,
                             const float* __restrict__ Wo,
                             u16* __restrict__ Wip, u16* __restrict__ Whp, u16* __restrict__ Wop) {
    int stride = gridDim.x * blockDim.x;
    int tid = blockIdx.x * blockDim.x + threadIdx.x;
    for (int i = tid; i < 128 * 160; i += stride) {
        int r = i / 160, c = i % 160;
        Wip[i] = (c < 133) ? f2bf(Wi[r * 133 + c]) : (u16)0;
        Whp[i] = (c < 142) ? f2bf(Wh[r * 142 + c]) : (u16)0;
    }
    for (int i = tid; i < 128 * 288; i += stride) {
        int r = i / 288, c = i % 288;
        float v = 0.f;
        if (c < 133)      v = Wo[r * 261 + c];
        else if (c >= 160) v = Wo[r * 261 + (c - 27)];
        Wop[i] = f2bf(v);
    }
}

// ---------------- bond pre-sum: sum_j f_bonds[a2b[:,j]] -> bf16 [N][32] ----------------
__global__ __launch_bounds__(256) void bond_gather(const float* __restrict__ fb, const int* __restrict__ a2b,
                                                   u16* __restrict__ outp) {
    long t = (long)blockIdx.x * 256 + threadIdx.x;
    int atom = (int)(t >> 4);
    int c2   = (int)(t & 15);
    if (atom >= N_ATOMS) return;
    int c0 = 2 * c2, c1 = c0 + 1;
    float s0 = 0.f, s1 = 0.f;
    if (c0 < BOND_FDIM) {
#pragma unroll
        for (int j = 0; j < MAX_NB; j++) {
            int idx = a2b[atom * 6 + j];
            const float* row = fb + (long)idx * BOND_FDIM;
            s0 += row[c0];
            if (c1 < BOND_FDIM) s1 += row[c1];
        }
    }
    *(u32*)(outp + (long)atom * 32 + c0) = pk2(s0, s1);
}

// ---------------- gather-relu-sum: dst[a] = sum_j relu(src[a2a[a,j]]) (bf16 128-wide) ---
__global__ __launch_bounds__(256) void gather_relu_sum(const u16* __restrict__ src,
                                                       const int* __restrict__ a2a,
                                                       u16* __restrict__ dst) {
    long t = (long)blockIdx.x * 256 + threadIdx.x;
    int atom = (int)(t >> 4);
    int c8   = (int)(t & 15) << 3;
    float s[8] = {0, 0, 0, 0, 0, 0, 0, 0};
#pragma unroll
    for (int j = 0; j < MAX_NB; j++) {
        int idx = a2a[atom * 6 + j];
        uint4 v = *(const uint4*)(src + (long)idx * 128 + c8);
        u32 w[4] = {v.x, v.y, v.z, v.w};
#pragma unroll
        for (int q = 0; q < 4; q++) {
            s[2 * q]     += fmaxf(__builtin_bit_cast(float, w[q] << 16), 0.f);
            s[2 * q + 1] += fmaxf(__builtin_bit_cast(float, w[q] & 0xFFFF0000u), 0.f);
        }
    }
    uint4 o;
    o.x = pk2(s[0], s[1]);
    o.y = pk2(s[2], s[3]);
    o.z = pk2(s[4], s[5]);
    o.w = pk2(s[6], s[7]);
    *(uint4*)(dst + (long)atom * 128 + c8) = o;
}

// ---------------- persistent DMA-pipelined GEMM with linear-store epilogue (r13) -------
#define ISSUE_SLOT(d, t)                                                              \
    do {                                                                              \
        long r_ = (t) * TILE + wave * 16 + lrow;                                      \
        if (r_ > N_ATOMS - 1) r_ = N_ATOMS - 1;                                       \
        u16* ab_ = AL + ((d) * WAVES + wave) * (KB0 * 512);                           \
        {                                                                             \
            const u16* p_ = A0 + r_ * (long)ldA0 + kg * 8;                            \
            _Pragma("unroll") for (int kb = 0; kb < KB0; kb++)                        \
                gl16(p_ + kb * 32, ab_ + kb * 512);                                   \
        }                                                                             \
        if constexpr (KB1 > 0) {                                                      \
            const u16* p_ = A1 + r_ * (long)ldA1 + kg * 8;                            \
            _Pragma("unroll") for (int kb = 0; kb < KB1; kb++)                        \
                a1v[d][kb] = *(const uint4*)(p_ + kb * 32);                           \
        }                                                                             \
        if constexpr (ADDX) {                                                         \
            _Pragma("unroll") for (int n = 0; n < 8; n++)                             \
                xv[d][n] = *(const uint2*)(Xadd + r_ * 128 + n * 16 + kg * 4);        \
        }                                                                             \
    } while (0)

template <int KB0, int KB1, bool ADDX, bool BIAS, int WAVES>
__global__ __launch_bounds__(WAVES * 64) void gemm_dma(
    const u16* __restrict__ A0, int ldA0,
    const u16* __restrict__ A1, int ldA1,
    const u16* __restrict__ Wp, const float* __restrict__ bias,
    const u16* __restrict__ Xadd, u16* __restrict__ Out) {
    constexpr int KB    = KB0 + KB1;
    constexpr int KP    = KB * 32;
    constexpr int TILE  = WAVES * 16;
    constexpr long NT   = (N_ATOMS + TILE - 1) / TILE;
    constexpr int WSLOTS = KB * 8;
    constexpr int DEPTH = 2;
    constexpr int NWAIT = KB0 + (KB1 > 0 ? KB1 : 0) + (ADDX ? 8 : 0) + 4;
    static_assert(NWAIT <= 63, "vmcnt range");
    __shared__ __align__(16) u16 lds[WSLOTS * 512 + DEPTH * WAVES * KB0 * 512 + WAVES * 2048];

    const int lane = threadIdx.x & 63;
    const int wave = threadIdx.x >> 6;
    const int lrow = lane & 15;
    const int kg   = lane >> 4;

    u16* WL = lds;
    u16* AL = lds + WSLOTS * 512;
    u16* SB = lds + WSLOTS * 512 + DEPTH * WAVES * KB0 * 512;

    for (int s = wave; s < WSLOTS; s += WAVES) {
        int kb = s >> 3, n = s & 7;
        gl16(Wp + (n * 16 + lrow) * KP + kb * 32 + kg * 8, WL + s * 512);
    }
    asm volatile("s_waitcnt vmcnt(0)" ::: "memory");
    __syncthreads();

    float4 b4[8];
#pragma unroll
    for (int n = 0; n < 8; n++)
        b4[n] = BIAS ? *(const float4*)(bias + n * 16 + kg * 4) : (float4){0.f, 0.f, 0.f, 0.f};

    const int G  = gridDim.x;
    const long t0 = blockIdx.x;

    uint4 a1v[DEPTH][KB1 > 0 ? KB1 : 1];
    uint2 xv[DEPTH][ADDX ? 8 : 1];

#pragma unroll
    for (int d = 0; d < DEPTH; d++) ISSUE_SLOT(d, t0 + (long)d * G);
    __builtin_amdgcn_sched_barrier(0);

#pragma unroll 1
    for (long tt = t0; tt < NT; tt += (long)DEPTH * G) {
#pragma unroll
        for (int d = 0; d < DEPTH; d++) {
            long t = tt + (long)d * G;
            if (t < NT) {
                asm volatile("s_waitcnt vmcnt(%0)" :: "n"(NWAIT) : "memory");
                __builtin_amdgcn_sched_barrier(0);

                const u16* ab = AL + (d * WAVES + wave) * (KB0 * 512);
                f32x4 acc[8];
#pragma unroll
                for (int n = 0; n < 8; n++) acc[n] = (f32x4){0.f, 0.f, 0.f, 0.f};
#pragma unroll
                for (int kb = 0; kb < KB; kb++) {
                    short8 af;
                    if (kb < KB0) af = *(const short8*)(ab + kb * 512 + lane * 8);
                    else          af = __builtin_bit_cast(short8, a1v[d][(kb - KB0) < KB1 ? (kb - KB0) : 0]);
#pragma unroll
                    for (int n = 0; n < 8; n++) {
                        short8 bf = *(const short8*)(WL + (kb * 8 + n) * 512 + lane * 8);
                        acc[n] = __builtin_amdgcn_mfma_f32_16x16x32_bf16(bf, af, acc[n], 0, 0, 0);
                    }
                }

                const long wrow0 = t * TILE + wave * 16;
                if (wrow0 < N_ATOMS) {
                    u16* sb = SB + wave * 2048;
#pragma unroll
                    for (int n = 0; n < 8; n++) {
                        float v0 = acc[n][0] + b4[n].x;
                        float v1 = acc[n][1] + b4[n].y;
                        float v2 = acc[n][2] + b4[n].z;
                        float v3 = acc[n][3] + b4[n].w;
                        if constexpr (ADDX) {
                            v0 += __builtin_bit_cast(float, xv[d][n].x << 16);
                            v1 += __builtin_bit_cast(float, xv[d][n].x & 0xFFFF0000u);
                            v2 += __builtin_bit_cast(float, xv[d][n].y << 16);
                            v3 += __builtin_bit_cast(float, xv[d][n].y & 0xFFFF0000u);
                        }
                        uint2 o;
                        o.x = pk2(v0, v1);
                        o.y = pk2(v2, v3);
                        int sboff = lrow * 256 + ((n * 32 + kg * 8) ^ ((lrow & 7) << 4));
                        *(uint2*)(sb + (sboff >> 1)) = o;
                    }
#pragma unroll
                    for (int i = 0; i < 4; i++) {
                        int R = i * 4 + (lane >> 4);
                        int B = ((lane & 15) * 16) ^ ((R & 7) << 4);
                        uint4 v = *(const uint4*)(sb + ((R * 256 + B) >> 1));
                        *(uint4*)(Out + wrow0 * 128 + i * 512 + lane * 8) = v;
                    }
                }
                __builtin_amdgcn_sched_barrier(0);
                ISSUE_SLOT(d, t + (long)DEPTH * G);
                __builtin_amdgcn_sched_barrier(0);
            }
        }
    }
}

// ---------------- fused Wo GEMM + molecule max-readout, 80-row blocks ----------------
// Block = 5 waves x 16 CONTIGUOUS rows = 80 rows = exactly 4 molecules (LCM(16,20)).
// No duplicated MFMA (r14's mistake). Epilogue: relu(acc+bias) -> bf16 -> swizzled
// LDS [80][128]; raw s_barrier (NOT __syncthreads: avoids compiler vmcnt(0) drain
// that would kill the DMA pipeline); waves 0..3 reduce one molecule each: per-lane
// max over 20 rows (ds_read_b32, XOR-swizzled), dot ffn_w, shuffle-sum, 1 store.
__global__ __launch_bounds__(320) void gemm_wo_red(
    const u16* __restrict__ fa, const u16* __restrict__ nsum,
    const u16* __restrict__ Wp, const float* __restrict__ bias,
    const float* __restrict__ ffn_w, const float* __restrict__ ffn_b,
    float* __restrict__ out) {
    constexpr int KB0 = 5, KB1 = 4, KB = 9, KP = 288;
    constexpr int WAVES = 5, DEPTH = 2, TILE = 80;
    constexpr long NT = N_MOLS / 4;  // 6250 tiles, exact
    constexpr int WSLOTS = KB * 8;   // 72 KB
    constexpr int NWAIT = KB0 + KB1 + 1;  // 5 DMA + 4 reg + <=1 out store
    // LDS: W 73728 + A slots 51200 + red 20480 = 145408 B
    __shared__ __align__(16) u16 lds[WSLOTS * 512 + DEPTH * WAVES * KB0 * 512 + 80 * 128];

    const int lane = threadIdx.x & 63;
    const int wave = threadIdx.x >> 6;
    const int lrow = lane & 15;
    const int kg   = lane >> 4;

    u16* WL  = lds;
    u16* AL  = lds + WSLOTS * 512;
    u16* RED = lds + WSLOTS * 512 + DEPTH * WAVES * KB0 * 512;

    for (int s = wave; s < WSLOTS; s += WAVES) {
        int kb = s >> 3, n = s & 7;
        gl16(Wp + (n * 16 + lrow) * KP + kb * 32 + kg * 8, WL + s * 512);
    }
    asm volatile("s_waitcnt vmcnt(0)" ::: "memory");
    __syncthreads();

    f32x4 bb[8];
#pragma unroll
    for (int n = 0; n < 8; n++)
        bb[n] = __builtin_bit_cast(f32x4, *(const float4*)(bias + n * 16 + kg * 4));
    // reduce-phase constants: lane handles cols 2*lane, 2*lane+1
    float fw0 = ffn_w[2 * lane], fw1 = ffn_w[2 * lane + 1];
    const float fb0 = ffn_b[0];

    const int G  = gridDim.x;
    const long t0 = blockIdx.x;

    uint4 a1v[DEPTH][KB1];

    auto issue = [&](int d, long t) {
        long tc = (t < NT) ? t : (NT - 1);
        long r = tc * TILE + wave * 16 + lrow;
        u16* ab = AL + ((d * WAVES + wave) * KB0) * 512;
        const u16* p = fa + r * 160 + kg * 8;
#pragma unroll
        for (int kb = 0; kb < KB0; kb++) gl16(p + kb * 32, ab + kb * 512);
        const u16* q = nsum + r * 128 + kg * 8;
#pragma unroll
        for (int kb = 0; kb < KB1; kb++) a1v[d][kb] = *(const uint4*)(q + kb * 32);
    };

#pragma unroll
    for (int d = 0; d < DEPTH; d++) issue(d, t0 + (long)d * G);
    __builtin_amdgcn_sched_barrier(0);

#pragma unroll 1
    for (long tt = t0; tt < NT; tt += (long)DEPTH * G) {
#pragma unroll
        for (int d = 0; d < DEPTH; d++) {
            long t = tt + (long)d * G;  // block-uniform
            if (t < NT) {
                asm volatile("s_waitcnt vmcnt(%0)" :: "n"(NWAIT) : "memory");
                __builtin_amdgcn_sched_barrier(0);

                const u16* ab = AL + ((d * WAVES + wave) * KB0) * 512;
                f32x4 acc[8];
#pragma unroll
                for (int n = 0; n < 8; n++) acc[n] = (f32x4){0.f, 0.f, 0.f, 0.f};
#pragma unroll
                for (int kb = 0; kb < KB; kb++) {
                    short8 af;
                    if (kb < KB0) af = *(const short8*)(ab + kb * 512 + lane * 8);
                    else          af = __builtin_bit_cast(short8, a1v[d][(kb - KB0) < KB1 ? (kb - KB0) : 0]);
#pragma unroll
                    for (int n = 0; n < 8; n++) {
                        short8 bf = *(const short8*)(WL + (kb * 8 + n) * 512 + lane * 8);
                        acc[n] = __builtin_amdgcn_mfma_f32_16x16x32_bf16(bf, af, acc[n], 0, 0, 0);
                    }
                }

                // epilogue: relu(acc+bias) -> bf16 -> swizzled RED[80][128]
                const int lr = wave * 16 + lrow;  // local row 0..79
#pragma unroll
                for (int n = 0; n < 8; n++) {
                    float v0 = fmaxf(acc[n][0] + bb[n][0], 0.f);
                    float v1 = fmaxf(acc[n][1] + bb[n][1], 0.f);
                    float v2 = fmaxf(acc[n][2] + bb[n][2], 0.f);
                    float v3 = fmaxf(acc[n][3] + bb[n][3], 0.f);
                    uint2 o;
                    o.x = pk2(v0, v1);
                    o.y = pk2(v2, v3);
                    int boff = lr * 256 + ((n * 32 + kg * 8) ^ ((lr & 7) << 4));
                    *(uint2*)(RED + (boff >> 1)) = o;
                }
                asm volatile("s_waitcnt lgkmcnt(0)" ::: "memory");
                __builtin_amdgcn_sched_barrier(0);
                __builtin_amdgcn_s_barrier();

                // reduce: wave w (<4) -> molecule t*4+w; lane -> cols 2l,2l+1
                if (wave < 4) {
                    float m0 = 0.f, m1 = 0.f;  // relu'd values are >= 0
#pragma unroll
                    for (int a = 0; a < APM; a++) {
                        int rr = wave * APM + a;
                        int boff = rr * 256 + ((4 * lane) ^ ((rr & 7) << 4));
                        u32 v = *(const u32*)(RED + (boff >> 1));
                        m0 = fmaxf(m0, bf2f((u16)(v & 0xFFFFu)));
                        m1 = fmaxf(m1, bf2f((u16)(v >> 16)));
                    }
                    float p = m0 * fw0 + m1 * fw1;
#pragma unroll
                    for (int sft = 1; sft <= 32; sft <<= 1) p += __shfl_xor(p, sft, 64);
                    if (lane == 0) out[t * 4 + wave] = p + fb0;
                }
                __builtin_amdgcn_s_barrier();

                __builtin_amdgcn_sched_barrier(0);
                issue(d, t + (long)DEPTH * G);
                __builtin_amdgcn_sched_barrier(0);
            }
        }
    }
}

// ---------------- fused Wi GEMM + fa conversion (r9/r13 exact) ----------
__global__ __launch_bounds__(512, 2) void gemm_wi(
    const float* __restrict__ FA, const u16* __restrict__ Wp,
    const float* __restrict__ bias, u16* __restrict__ fa16, u16* __restrict__ Out) {
    constexpr int KB = 5, KP = 160, TILE = 128;
    constexpr long NT = (N_ATOMS + TILE - 1) / TILE;
    constexpr int WSLOTS = KB * 8;
    constexpr int DEPTH = 2;
    constexpr int NWAIT = 23;
    __shared__ __align__(16) u16 WL[WSLOTS * 512];

    const int lane = threadIdx.x & 63;
    const int wave = threadIdx.x >> 6;
    const int lrow = lane & 15;
    const int kg   = lane >> 4;

    for (int s = wave; s < WSLOTS; s += 8) {
        int kb = s >> 3, n = s & 7;
        gl16(Wp + (n * 16 + lrow) * KP + kb * 32 + kg * 8, WL + s * 512);
    }
    asm volatile("s_waitcnt vmcnt(0)" ::: "memory");
    __syncthreads();

    float4 b4[8];
#pragma unroll
    for (int n = 0; n < 8; n++) b4[n] = *(const float4*)(bias + n * 16 + kg * 4);

    const int G  = gridDim.x;
    const long t0 = blockIdx.x;

    uint4 af32[DEPTH][4][2];
    uint4 a4[DEPTH];
    float a4s[DEPTH];

#define WI_ISSUE(d, t)                                                         \
    do {                                                                       \
        long r_ = (t) * TILE + wave * 16 + lrow;                               \
        if (r_ > N_ATOMS - 1) r_ = N_ATOMS - 1;                                \
        const float* p_ = FA + r_ * (long)ATOM_FDIM + kg * 8;                  \
        _Pragma("unroll") for (int kb = 0; kb < 4; kb++) {                     \
            af32[d][kb][0] = *(const uint4*)(p_ + kb * 32);                    \
            af32[d][kb][1] = *(const uint4*)(p_ + kb * 32 + 4);                \
        }                                                                      \
        if (kg == 0) {                                                         \
            const float* q_ = FA + r_ * (long)ATOM_FDIM + 128;                 \
            a4[d]  = *(const uint4*)(q_);                                      \
            a4s[d] = q_[4];                                                    \
        }                                                                      \
    } while (0)

#pragma unroll
    for (int d = 0; d < DEPTH; d++) WI_ISSUE(d, t0 + (long)d * G);
    __builtin_amdgcn_sched_barrier(0);

#pragma unroll 1
    for (long tt = t0; tt < NT; tt += (long)DEPTH * G) {
#pragma unroll
        for (int d = 0; d < DEPTH; d++) {
            long t = tt + (long)d * G;
            if (t < NT) {
                asm volatile("s_waitcnt vmcnt(%0)" :: "n"(NWAIT) : "memory");
                __builtin_amdgcn_sched_barrier(0);

                long r = t * TILE + wave * 16 + lrow;
                bool wr = (r < N_ATOMS);

                short8 frag[5];
#pragma unroll
                for (int kb = 0; kb < 4; kb++) {
                    float4 lo = __builtin_bit_cast(float4, af32[d][kb][0]);
                    float4 hi = __builtin_bit_cast(float4, af32[d][kb][1]);
                    uint4 pk;
                    pk.x = pk2(lo.x, lo.y);
                    pk.y = pk2(lo.z, lo.w);
                    pk.z = pk2(hi.x, hi.y);
                    pk.w = pk2(hi.z, hi.w);
                    frag[kb] = __builtin_bit_cast(short8, pk);
                }
                {
                    uint4 pk = (uint4){0, 0, 0, 0};
                    if (kg == 0) {
                        float4 q = __builtin_bit_cast(float4, a4[d]);
                        pk.x = pk2(q.x, q.y);
                        pk.y = pk2(q.z, q.w);
                        pk.z = pk2(a4s[d], 0.f);
                    }
                    frag[4] = __builtin_bit_cast(short8, pk);
                }

                f32x4 acc[8];
#pragma unroll
                for (int n = 0; n < 8; n++) acc[n] = (f32x4){0.f, 0.f, 0.f, 0.f};
#pragma unroll
                for (int kb = 0; kb < 5; kb++) {
#pragma unroll
                    for (int n = 0; n < 8; n++) {
                        short8 bf = *(const short8*)(WL + (kb * 8 + n) * 512 + lane * 8);
                        acc[n] = __builtin_amdgcn_mfma_f32_16x16x32_bf16(bf, frag[kb], acc[n], 0, 0, 0);
                    }
                }

                if (wr) {
#pragma unroll
                    for (int kb = 0; kb < 5; kb++)
                        *(uint4*)(fa16 + r * 160 + kb * 32 + kg * 8) = __builtin_bit_cast(uint4, frag[kb]);
#pragma unroll
                    for (int n = 0; n < 8; n++) {
                        uint2 o;
                        o.x = pk2(acc[n][0] + b4[n].x, acc[n][1] + b4[n].y);
                        o.y = pk2(acc[n][2] + b4[n].z, acc[n][3] + b4[n].w);
                        *(uint2*)(Out + r * 128 + n * 16 + kg * 4) = o;
                    }
                }
                __builtin_amdgcn_sched_barrier(0);
                WI_ISSUE(d, t + (long)DEPTH * G);
                __builtin_amdgcn_sched_barrier(0);
            }
        }
    }
#undef WI_ISSUE
}

extern "C" void kernel_launch(void* const* d_in, const int* in_sizes, int n_in,
                              void* d_out, int out_size, void* d_ws, size_t ws_size,
                              hipStream_t stream) {
    const float* f_atoms = (const float*)d_in[0];
    const float* f_bonds = (const float*)d_in[1];
    const float* Wi_w = (const float*)d_in[2];
    const float* Wi_b = (const float*)d_in[3];
    const float* Wh_w = (const float*)d_in[4];
    const float* Wh_b = (const float*)d_in[5];
    const float* Wo_w = (const float*)d_in[6];
    const float* Wo_b = (const float*)d_in[7];
    const float* ffn_w = (const float*)d_in[8];
    const float* ffn_b = (const float*)d_in[9];
    const int* a2a = (const int*)d_in[10];
    const int* a2b = (const int*)d_in[11];
    float* out = (float*)d_out;

    char* ws = (char*)d_ws;
    u16* fa    = (u16*)(ws);                  // 160,000,000
    u16* xb    = (u16*)(ws + 160000000L);     // 128,000,000  (pre-relu x)
    u16* msgA  = (u16*)(ws + 288000000L);     // 128,000,000
    u16* msgB  = (u16*)(ws + 416000000L);     // 128,000,000
    u16* nsum  = (u16*)(ws + 544000000L);     // 128,000,000
    u16* nbond = (u16*)(ws + 672000000L);     // 32,000,000
    u16* Wip   = (u16*)(ws + 704000000L);     // 40960
    u16* Whp   = (u16*)(ws + 704040960L);     // 40960
    u16* Wop   = (u16*)(ws + 704081920L);     // 73728

    prep_weights<<<64, 256, 0, stream>>>(Wi_w, Wh_w, Wo_w, Wip, Whp, Wop);
    bond_gather<<<31250, 256, 0, stream>>>(f_bonds, a2b, nbond);

    // x = f_atoms @ Wi^T + b (pre-relu); also emits padded bf16 fa
    gemm_wi<<<256, 512, 0, stream>>>(f_atoms, Wip, Wi_b, fa, xb);

    // depth 1: A0=nsum (DMA), A1=nbond (reg), X=xb (reg)
    gather_relu_sum<<<31250, 256, 0, stream>>>(xb, a2a, nsum);
    gemm_dma<4, 1, true, true, 8><<<256, 512, 0, stream>>>(
        nsum, 128, nbond, 32, Whp, Wh_b, xb, msgA);
    // depth 2
    gather_relu_sum<<<31250, 256, 0, stream>>>(msgA, a2a, nsum);
    gemm_dma<4, 1, true, true, 8><<<256, 512, 0, stream>>>(
        nsum, 128, nbond, 32, Whp, Wh_b, xb, msgB);
    // final: fused Wo + molecule-max readout (80-row blocks = 4 mols, no dup MFMA)
    gather_relu_sum<<<31250, 256, 0, stream>>>(msgB, a2a, nsum);
    gemm_wo_red<<<250, 320, 0, stream>>>(fa, nsum, Wop, Wo_b, ffn_w, ffn_b, out);
}

// Round 17
// 814.526 us; speedup vs baseline: 1.0241x; 1.0070x over previous
//
#include <hip/hip_runtime.h>
#include <hip/hip_bf16.h>

#define N_ATOMS   500000
#define N_BONDS   1000000
#define MAX_NB    6
#define ATOM_FDIM 133
#define BOND_FDIM 14
#define HIDDEN    128
#define N_MOLS    25000
#define APM       20

typedef __attribute__((ext_vector_type(8))) short short8;
typedef __attribute__((ext_vector_type(4))) float f32x4;
typedef __attribute__((ext_vector_type(4))) unsigned int u32x4;
typedef unsigned short u16;
typedef unsigned int   u32;

__device__ __forceinline__ float bf2f(u16 u) {
    u32 t = ((u32)u) << 16;
    return __builtin_bit_cast(float, t);
}
__device__ __forceinline__ u16 f2bf(float f) {
    u32 t = __builtin_bit_cast(u32, f);
    t += 0x7FFFu + ((t >> 16) & 1u);
    return (u16)(t >> 16);
}
__device__ __forceinline__ u32 pk2(float a, float b) {
    return (u32)f2bf(a) | ((u32)f2bf(b) << 16);
}

// async global->LDS, 16B per lane. LDS dest = uniform base + lane*16; global src per-lane.
__device__ __forceinline__ void gl16(const u16* g, u16* l) {
    __builtin_amdgcn_global_load_lds(
        (__attribute__((address_space(1))) void*)(g),
        (__attribute__((address_space(3))) void*)(l), 16, 0, 0);
}

// ---------------- weight prep: fp32 -> padded bf16 ----------------
__global__ void prep_weights(const float* __restrict__ Wi, const float* __restrict__ Wh,
                             const float* __restrict__ Wo,
                             u16* __restrict__ Wip, u16* __restrict__ Whp, u16* __restrict__ Wop) {
    int stride = gridDim.x * blockDim.x;
    int tid = blockIdx.x * blockDim.x + threadIdx.x;
    for (int i = tid; i < 128 * 160; i += stride) {
        int r = i / 160, c = i % 160;
        Wip[i] = (c < 133) ? f2bf(Wi[r * 133 + c]) : (u16)0;
        Whp[i] = (c < 142) ? f2bf(Wh[r * 142 + c]) : (u16)0;
    }
    for (int i = tid; i < 128 * 288; i += stride) {
        int r = i / 288, c = i % 288;
        float v = 0.f;
        if (c < 133)      v = Wo[r * 261 + c];
        else if (c >= 160) v = Wo[r * 261 + (c - 27)];
        Wop[i] = f2bf(v);
    }
}

// ---------------- bond pre-sum: sum_j f_bonds[a2b[:,j]] -> bf16 [N][32] ----------------
__global__ __launch_bounds__(256) void bond_gather(const float* __restrict__ fb, const int* __restrict__ a2b,
                                                   u16* __restrict__ outp) {
    long t = (long)blockIdx.x * 256 + threadIdx.x;
    int atom = (int)(t >> 4);
    int c2   = (int)(t & 15);
    if (atom >= N_ATOMS) return;
    int c0 = 2 * c2, c1 = c0 + 1;
    float s0 = 0.f, s1 = 0.f;
    if (c0 < BOND_FDIM) {
#pragma unroll
        for (int j = 0; j < MAX_NB; j++) {
            int idx = a2b[atom * 6 + j];
            const float* row = fb + (long)idx * BOND_FDIM;
            s0 += row[c0];
            if (c1 < BOND_FDIM) s1 += row[c1];
        }
    }
    *(u32*)(outp + (long)atom * 32 + c0) = pk2(s0, s1);
}

// ---------------- gather-relu-sum: dst[a] = sum_j relu(src[a2a[a,j]]) (bf16 128-wide) ---
__global__ __launch_bounds__(256) void gather_relu_sum(const u16* __restrict__ src,
                                                       const int* __restrict__ a2a,
                                                       u16* __restrict__ dst) {
    long t = (long)blockIdx.x * 256 + threadIdx.x;
    int atom = (int)(t >> 4);
    int c8   = (int)(t & 15) << 3;
    float s[8] = {0, 0, 0, 0, 0, 0, 0, 0};
#pragma unroll
    for (int j = 0; j < MAX_NB; j++) {
        int idx = a2a[atom * 6 + j];
        uint4 v = *(const uint4*)(src + (long)idx * 128 + c8);
        u32 w[4] = {v.x, v.y, v.z, v.w};
#pragma unroll
        for (int q = 0; q < 4; q++) {
            s[2 * q]     += fmaxf(__builtin_bit_cast(float, w[q] << 16), 0.f);
            s[2 * q + 1] += fmaxf(__builtin_bit_cast(float, w[q] & 0xFFFF0000u), 0.f);
        }
    }
    uint4 o;
    o.x = pk2(s[0], s[1]);
    o.y = pk2(s[2], s[3]);
    o.z = pk2(s[4], s[5]);
    o.w = pk2(s[6], s[7]);
    *(uint4*)(dst + (long)atom * 128 + c8) = o;
}

// ---------------- fused gather + Wh GEMM ----------------
// msgOut = relu-sum-gather(pool) [k 0..127] (+nbond k 128..159) @ Wh^T + bias + x.
// Key: with swapped-operand MFMA, each lane's gathered relu-sum of its row's 6
// neighbor fragments IS its own MFMA A-fragment (lane=row lrow, k=kb*32+kg*8) ->
// no LDS staging, no cross-lane. 4 passes of g[6] only (24 VGPR, r2-proven, no
// demotion); 16 waves/CU (LDS 72KB, 2 blocks/CU) give in-flight bytes.
// Anti-thrash (r3 lesson): NT linear stores -> no L3 alloc for output; pool stays
// L3-resident. Eliminates the 256MB nsum round-trip of depth-1.
__global__ __launch_bounds__(512, 4) void gemm_gwh(
    const u16* __restrict__ pool, const int* __restrict__ a2a,
    const u16* __restrict__ nbond, const u16* __restrict__ Wp,
    const float* __restrict__ bias, u16* __restrict__ Out) {
    constexpr int KB = 5, KP = 160;
    constexpr int WAVES = 8, TILE = 128;
    constexpr long NT = (N_ATOMS + TILE - 1) / TILE;
    constexpr int WSLOTS = KB * 8;  // 40 slots = 40 KB
    __shared__ __align__(16) u16 lds[WSLOTS * 512 + WAVES * 2048];  // 72 KB

    const int lane = threadIdx.x & 63;
    const int wave = threadIdx.x >> 6;
    const int lrow = lane & 15;
    const int kg   = lane >> 4;

    u16* WL = lds;
    u16* SB = lds + WSLOTS * 512;

    for (int s = wave; s < WSLOTS; s += WAVES) {
        int kb = s >> 3, n = s & 7;
        gl16(Wp + (n * 16 + lrow) * KP + kb * 32 + kg * 8, WL + s * 512);
    }
    asm volatile("s_waitcnt vmcnt(0)" ::: "memory");
    __syncthreads();

    float4 b4[8];
#pragma unroll
    for (int n = 0; n < 8; n++) b4[n] = *(const float4*)(bias + n * 16 + kg * 4);

    const int G = gridDim.x;
#pragma unroll 1
    for (long t = blockIdx.x; t < NT; t += G) {
        long r = t * TILE + wave * 16 + lrow;
        if (r > N_ATOMS - 1) r = N_ATOMS - 1;

        // neighbor indices for this lane's row (kg groups duplicate; L1 broadcast)
        const int* ip = a2a + r * 6;
        uint2 i01 = *(const uint2*)(ip);
        uint2 i23 = *(const uint2*)(ip + 2);
        uint2 i45 = *(const uint2*)(ip + 4);
        u32 idx[6] = {i01.x, i01.y, i23.x, i23.y, i45.x, i45.y};

        // gathered A-fragments: 4 passes, 6 loads in flight each
        short8 frag[5];
#pragma unroll
        for (int p = 0; p < 4; p++) {
            uint4 g[6];
#pragma unroll
            for (int j = 0; j < 6; j++)
                g[j] = *(const uint4*)(pool + (long)idx[j] * 128 + p * 32 + kg * 8);
            float s[8] = {0, 0, 0, 0, 0, 0, 0, 0};
#pragma unroll
            for (int j = 0; j < 6; j++) {
                u32 w4[4] = {g[j].x, g[j].y, g[j].z, g[j].w};
#pragma unroll
                for (int q = 0; q < 4; q++) {
                    s[2 * q]     += fmaxf(__builtin_bit_cast(float, w4[q] << 16), 0.f);
                    s[2 * q + 1] += fmaxf(__builtin_bit_cast(float, w4[q] & 0xFFFF0000u), 0.f);
                }
            }
            uint4 pk;
            pk.x = pk2(s[0], s[1]);
            pk.y = pk2(s[2], s[3]);
            pk.z = pk2(s[4], s[5]);
            pk.w = pk2(s[6], s[7]);
            frag[p] = __builtin_bit_cast(short8, pk);
        }
        frag[4] = __builtin_bit_cast(short8, *(const uint4*)(nbond + r * 32 + kg * 8));

        uint2 xv[8];
#pragma unroll
        for (int n = 0; n < 8; n++)
            xv[n] = *(const uint2*)(pool + r * 128 + n * 16 + kg * 4);

        f32x4 acc[8];
#pragma unroll
        for (int n = 0; n < 8; n++) acc[n] = (f32x4){0.f, 0.f, 0.f, 0.f};
#pragma unroll
        for (int kb = 0; kb < 5; kb++) {
#pragma unroll
            for (int n = 0; n < 8; n++) {
                short8 bf = *(const short8*)(WL + (kb * 8 + n) * 512 + lane * 8);
                acc[n] = __builtin_amdgcn_mfma_f32_16x16x32_bf16(bf, frag[kb], acc[n], 0, 0, 0);
            }
        }

        const long wrow0 = t * TILE + wave * 16;
        if (wrow0 < N_ATOMS) {  // wave-uniform (N_ATOMS % 16 == 0)
            u16* sb = SB + wave * 2048;
#pragma unroll
            for (int n = 0; n < 8; n++) {
                float v0 = acc[n][0] + b4[n].x + __builtin_bit_cast(float, xv[n].x << 16);
                float v1 = acc[n][1] + b4[n].y + __builtin_bit_cast(float, xv[n].x & 0xFFFF0000u);
                float v2 = acc[n][2] + b4[n].z + __builtin_bit_cast(float, xv[n].y << 16);
                float v3 = acc[n][3] + b4[n].w + __builtin_bit_cast(float, xv[n].y & 0xFFFF0000u);
                uint2 o;
                o.x = pk2(v0, v1);
                o.y = pk2(v2, v3);
                int sboff = lrow * 256 + ((n * 32 + kg * 8) ^ ((lrow & 7) << 4));
                *(uint2*)(sb + (sboff >> 1)) = o;
            }
            // linear 4KB per-wave store, NON-TEMPORAL (no L3 alloc -> pool stays hot)
#pragma unroll
            for (int i = 0; i < 4; i++) {
                int R = i * 4 + (lane >> 4);
                int B = ((lane & 15) * 16) ^ ((R & 7) << 4);
                u32x4 v = *(const u32x4*)(sb + ((R * 256 + B) >> 1));
                __builtin_nontemporal_store(v, (u32x4*)(Out + wrow0 * 128 + i * 512 + lane * 8));
            }
        }
    }
}

// ---------------- persistent DMA-pipelined GEMM with linear-store epilogue (r13) -------
#define ISSUE_SLOT(d, t)                                                              \
    do {                                                                              \
        long r_ = (t) * TILE + wave * 16 + lrow;                                      \
        if (r_ > N_ATOMS - 1) r_ = N_ATOMS - 1;                                       \
        u16* ab_ = AL + ((d) * WAVES + wave) * (KB0 * 512);                           \
        {                                                                             \
            const u16* p_ = A0 + r_ * (long)ldA0 + kg * 8;                            \
            _Pragma("unroll") for (int kb = 0; kb < KB0; kb++)                        \
                gl16(p_ + kb * 32, ab_ + kb * 512);                                   \
        }                                                                             \
        if constexpr (KB1 > 0) {                                                      \
            const u16* p_ = A1 + r_ * (long)ldA1 + kg * 8;                            \
            _Pragma("unroll") for (int kb = 0; kb < KB1; kb++)                        \
                a1v[d][kb] = *(const uint4*)(p_ + kb * 32);                           \
        }                                                                             \
        if constexpr (ADDX) {                                                         \
            _Pragma("unroll") for (int n = 0; n < 8; n++)                             \
                xv[d][n] = *(const uint2*)(Xadd + r_ * 128 + n * 16 + kg * 4);        \
        }                                                                             \
    } while (0)

template <int KB0, int KB1, bool ADDX, bool BIAS, int WAVES>
__global__ __launch_bounds__(WAVES * 64) void gemm_dma(
    const u16* __restrict__ A0, int ldA0,
    const u16* __restrict__ A1, int ldA1,
    const u16* __restrict__ Wp, const float* __restrict__ bias,
    const u16* __restrict__ Xadd, u16* __restrict__ Out) {
    constexpr int KB    = KB0 + KB1;
    constexpr int KP    = KB * 32;
    constexpr int TILE  = WAVES * 16;
    constexpr long NT   = (N_ATOMS + TILE - 1) / TILE;
    constexpr int WSLOTS = KB * 8;
    constexpr int DEPTH = 2;
    constexpr int NWAIT = KB0 + (KB1 > 0 ? KB1 : 0) + (ADDX ? 8 : 0) + 4;
    static_assert(NWAIT <= 63, "vmcnt range");
    __shared__ __align__(16) u16 lds[WSLOTS * 512 + DEPTH * WAVES * KB0 * 512 + WAVES * 2048];

    const int lane = threadIdx.x & 63;
    const int wave = threadIdx.x >> 6;
    const int lrow = lane & 15;
    const int kg   = lane >> 4;

    u16* WL = lds;
    u16* AL = lds + WSLOTS * 512;
    u16* SB = lds + WSLOTS * 512 + DEPTH * WAVES * KB0 * 512;

    for (int s = wave; s < WSLOTS; s += WAVES) {
        int kb = s >> 3, n = s & 7;
        gl16(Wp + (n * 16 + lrow) * KP + kb * 32 + kg * 8, WL + s * 512);
    }
    asm volatile("s_waitcnt vmcnt(0)" ::: "memory");
    __syncthreads();

    float4 b4[8];
#pragma unroll
    for (int n = 0; n < 8; n++)
        b4[n] = BIAS ? *(const float4*)(bias + n * 16 + kg * 4) : (float4){0.f, 0.f, 0.f, 0.f};

    const int G  = gridDim.x;
    const long t0 = blockIdx.x;

    uint4 a1v[DEPTH][KB1 > 0 ? KB1 : 1];
    uint2 xv[DEPTH][ADDX ? 8 : 1];

#pragma unroll
    for (int d = 0; d < DEPTH; d++) ISSUE_SLOT(d, t0 + (long)d * G);
    __builtin_amdgcn_sched_barrier(0);

#pragma unroll 1
    for (long tt = t0; tt < NT; tt += (long)DEPTH * G) {
#pragma unroll
        for (int d = 0; d < DEPTH; d++) {
            long t = tt + (long)d * G;
            if (t < NT) {
                asm volatile("s_waitcnt vmcnt(%0)" :: "n"(NWAIT) : "memory");
                __builtin_amdgcn_sched_barrier(0);

                const u16* ab = AL + (d * WAVES + wave) * (KB0 * 512);
                f32x4 acc[8];
#pragma unroll
                for (int n = 0; n < 8; n++) acc[n] = (f32x4){0.f, 0.f, 0.f, 0.f};
#pragma unroll
                for (int kb = 0; kb < KB; kb++) {
                    short8 af;
                    if (kb < KB0) af = *(const short8*)(ab + kb * 512 + lane * 8);
                    else          af = __builtin_bit_cast(short8, a1v[d][(kb - KB0) < KB1 ? (kb - KB0) : 0]);
#pragma unroll
                    for (int n = 0; n < 8; n++) {
                        short8 bf = *(const short8*)(WL + (kb * 8 + n) * 512 + lane * 8);
                        acc[n] = __builtin_amdgcn_mfma_f32_16x16x32_bf16(bf, af, acc[n], 0, 0, 0);
                    }
                }

                const long wrow0 = t * TILE + wave * 16;
                if (wrow0 < N_ATOMS) {
                    u16* sb = SB + wave * 2048;
#pragma unroll
                    for (int n = 0; n < 8; n++) {
                        float v0 = acc[n][0] + b4[n].x;
                        float v1 = acc[n][1] + b4[n].y;
                        float v2 = acc[n][2] + b4[n].z;
                        float v3 = acc[n][3] + b4[n].w;
                        if constexpr (ADDX) {
                            v0 += __builtin_bit_cast(float, xv[d][n].x << 16);
                            v1 += __builtin_bit_cast(float, xv[d][n].x & 0xFFFF0000u);
                            v2 += __builtin_bit_cast(float, xv[d][n].y << 16);
                            v3 += __builtin_bit_cast(float, xv[d][n].y & 0xFFFF0000u);
                        }
                        uint2 o;
                        o.x = pk2(v0, v1);
                        o.y = pk2(v2, v3);
                        int sboff = lrow * 256 + ((n * 32 + kg * 8) ^ ((lrow & 7) << 4));
                        *(uint2*)(sb + (sboff >> 1)) = o;
                    }
#pragma unroll
                    for (int i = 0; i < 4; i++) {
                        int R = i * 4 + (lane >> 4);
                        int B = ((lane & 15) * 16) ^ ((R & 7) << 4);
                        uint4 v = *(const uint4*)(sb + ((R * 256 + B) >> 1));
                        *(uint4*)(Out + wrow0 * 128 + i * 512 + lane * 8) = v;
                    }
                }
                __builtin_amdgcn_sched_barrier(0);
                ISSUE_SLOT(d, t + (long)DEPTH * G);
                __builtin_amdgcn_sched_barrier(0);
            }
        }
    }
}

// ---------------- fused Wi GEMM + fa conversion (r9/r13 exact) ----------
__global__ __launch_bounds__(512, 2) void gemm_wi(
    const float* __restrict__ FA, const u16* __restrict__ Wp,
    const float* __restrict__ bias, u16* __restrict__ fa16, u16* __restrict__ Out) {
    constexpr int KB = 5, KP = 160, TILE = 128;
    constexpr long NT = (N_ATOMS + TILE - 1) / TILE;
    constexpr int WSLOTS = KB * 8;
    constexpr int DEPTH = 2;
    constexpr int NWAIT = 23;
    __shared__ __align__(16) u16 WL[WSLOTS * 512];

    const int lane = threadIdx.x & 63;
    const int wave = threadIdx.x >> 6;
    const int lrow = lane & 15;
    const int kg   = lane >> 4;

    for (int s = wave; s < WSLOTS; s += 8) {
        int kb = s >> 3, n = s & 7;
        gl16(Wp + (n * 16 + lrow) * KP + kb * 32 + kg * 8, WL + s * 512);
    }
    asm volatile("s_waitcnt vmcnt(0)" ::: "memory");
    __syncthreads();

    float4 b4[8];
#pragma unroll
    for (int n = 0; n < 8; n++) b4[n] = *(const float4*)(bias + n * 16 + kg * 4);

    const int G  = gridDim.x;
    const long t0 = blockIdx.x;

    uint4 af32[DEPTH][4][2];
    uint4 a4[DEPTH];
    float a4s[DEPTH];

#define WI_ISSUE(d, t)                                                         \
    do {                                                                       \
        long r_ = (t) * TILE + wave * 16 + lrow;                               \
        if (r_ > N_ATOMS - 1) r_ = N_ATOMS - 1;                                \
        const float* p_ = FA + r_ * (long)ATOM_FDIM + kg * 8;                  \
        _Pragma("unroll") for (int kb = 0; kb < 4; kb++) {                     \
            af32[d][kb][0] = *(const uint4*)(p_ + kb * 32);                    \
            af32[d][kb][1] = *(const uint4*)(p_ + kb * 32 + 4);                \
        }                                                                      \
        if (kg == 0) {                                                         \
            const float* q_ = FA + r_ * (long)ATOM_FDIM + 128;                 \
            a4[d]  = *(const uint4*)(q_);                                      \
            a4s[d] = q_[4];                                                    \
        }                                                                      \
    } while (0)

#pragma unroll
    for (int d = 0; d < DEPTH; d++) WI_ISSUE(d, t0 + (long)d * G);
    __builtin_amdgcn_sched_barrier(0);

#pragma unroll 1
    for (long tt = t0; tt < NT; tt += (long)DEPTH * G) {
#pragma unroll
        for (int d = 0; d < DEPTH; d++) {
            long t = tt + (long)d * G;
            if (t < NT) {
                asm volatile("s_waitcnt vmcnt(%0)" :: "n"(NWAIT) : "memory");
                __builtin_amdgcn_sched_barrier(0);

                long r = t * TILE + wave * 16 + lrow;
                bool wr = (r < N_ATOMS);

                short8 frag[5];
#pragma unroll
                for (int kb = 0; kb < 4; kb++) {
                    float4 lo = __builtin_bit_cast(float4, af32[d][kb][0]);
                    float4 hi = __builtin_bit_cast(float4, af32[d][kb][1]);
                    uint4 pk;
                    pk.x = pk2(lo.x, lo.y);
                    pk.y = pk2(lo.z, lo.w);
                    pk.z = pk2(hi.x, hi.y);
                    pk.w = pk2(hi.z, hi.w);
                    frag[kb] = __builtin_bit_cast(short8, pk);
                }
                {
                    uint4 pk = (uint4){0, 0, 0, 0};
                    if (kg == 0) {
                        float4 q = __builtin_bit_cast(float4, a4[d]);
                        pk.x = pk2(q.x, q.y);
                        pk.y = pk2(q.z, q.w);
                        pk.z = pk2(a4s[d], 0.f);
                    }
                    frag[4] = __builtin_bit_cast(short8, pk);
                }

                f32x4 acc[8];
#pragma unroll
                for (int n = 0; n < 8; n++) acc[n] = (f32x4){0.f, 0.f, 0.f, 0.f};
#pragma unroll
                for (int kb = 0; kb < 5; kb++) {
#pragma unroll
                    for (int n = 0; n < 8; n++) {
                        short8 bf = *(const short8*)(WL + (kb * 8 + n) * 512 + lane * 8);
                        acc[n] = __builtin_amdgcn_mfma_f32_16x16x32_bf16(bf, frag[kb], acc[n], 0, 0, 0);
                    }
                }

                if (wr) {
#pragma unroll
                    for (int kb = 0; kb < 5; kb++)
                        *(uint4*)(fa16 + r * 160 + kb * 32 + kg * 8) = __builtin_bit_cast(uint4, frag[kb]);
#pragma unroll
                    for (int n = 0; n < 8; n++) {
                        uint2 o;
                        o.x = pk2(acc[n][0] + b4[n].x, acc[n][1] + b4[n].y);
                        o.y = pk2(acc[n][2] + b4[n].z, acc[n][3] + b4[n].w);
                        *(uint2*)(Out + r * 128 + n * 16 + kg * 4) = o;
                    }
                }
                __builtin_amdgcn_sched_barrier(0);
                WI_ISSUE(d, t + (long)DEPTH * G);
                __builtin_amdgcn_sched_barrier(0);
            }
        }
    }
#undef WI_ISSUE
}

// ---------------- readout: per-mol max over 20 atoms (w/ relu) then dot ffn_w ----------
__global__ __launch_bounds__(256) void readout(const u16* __restrict__ ah,
                                               const float* __restrict__ ffn_w,
                                               const float* __restrict__ ffn_b,
                                               float* __restrict__ out) {
    int mol  = blockIdx.x * 4 + (threadIdx.x >> 6);
    int lane = threadIdx.x & 63;
    if (mol >= N_MOLS) return;
    float m0 = -1e30f, m1 = -1e30f;
    const u16* base = ah + (long)mol * APM * 128 + 2 * lane;
#pragma unroll
    for (int a = 0; a < APM; a++) {
        u32 v = *(const u32*)(base + a * 128);
        m0 = fmaxf(m0, bf2f((u16)(v & 0xFFFFu)));
        m1 = fmaxf(m1, bf2f((u16)(v >> 16)));
    }
    m0 = fmaxf(m0, 0.f);
    m1 = fmaxf(m1, 0.f);
    float p = m0 * ffn_w[2 * lane] + m1 * ffn_w[2 * lane + 1];
#pragma unroll
    for (int off = 32; off > 0; off >>= 1) p += __shfl_down(p, off);
    if (lane == 0) out[mol] = p + ffn_b[0];
}

extern "C" void kernel_launch(void* const* d_in, const int* in_sizes, int n_in,
                              void* d_out, int out_size, void* d_ws, size_t ws_size,
                              hipStream_t stream) {
    const float* f_atoms = (const float*)d_in[0];
    const float* f_bonds = (const float*)d_in[1];
    const float* Wi_w = (const float*)d_in[2];
    const float* Wi_b = (const float*)d_in[3];
    const float* Wh_w = (const float*)d_in[4];
    const float* Wh_b = (const float*)d_in[5];
    const float* Wo_w = (const float*)d_in[6];
    const float* Wo_b = (const float*)d_in[7];
    const float* ffn_w = (const float*)d_in[8];
    const float* ffn_b = (const float*)d_in[9];
    const int* a2a = (const int*)d_in[10];
    const int* a2b = (const int*)d_in[11];
    float* out = (float*)d_out;

    char* ws = (char*)d_ws;
    u16* fa    = (u16*)(ws);                  // 160,000,000
    u16* xb    = (u16*)(ws + 160000000L);     // 128,000,000  (pre-relu x)
    u16* msgA  = (u16*)(ws + 288000000L);     // 128,000,000
    u16* msgB  = (u16*)(ws + 416000000L);     // 128,000,000
    u16* nsum  = (u16*)(ws + 544000000L);     // 128,000,000
    u16* nbond = (u16*)(ws + 672000000L);     // 32,000,000
    u16* Wip   = (u16*)(ws + 704000000L);     // 40960
    u16* Whp   = (u16*)(ws + 704040960L);     // 40960
    u16* Wop   = (u16*)(ws + 704081920L);     // 73728

    prep_weights<<<64, 256, 0, stream>>>(Wi_w, Wh_w, Wo_w, Wip, Whp, Wop);
    bond_gather<<<31250, 256, 0, stream>>>(f_bonds, a2b, nbond);

    // x = f_atoms @ Wi^T + b (pre-relu); also emits padded bf16 fa
    gemm_wi<<<256, 512, 0, stream>>>(f_atoms, Wip, Wi_b, fa, xb);

    // depth 1: FUSED gather+Wh (A/B experiment vs split depth-2)
    gemm_gwh<<<512, 512, 0, stream>>>(xb, a2a, nbond, Whp, Wh_b, msgA);

    // depth 2: split (r13 known-good) -- in-run A/B baseline
    gather_relu_sum<<<31250, 256, 0, stream>>>(msgA, a2a, nsum);
    gemm_dma<4, 1, true, true, 8><<<256, 512, 0, stream>>>(
        nsum, 128, nbond, 32, Whp, Wh_b, xb, msgB);

    // final: gather + Wo + readout (r13 exact)
    gather_relu_sum<<<31250, 256, 0, stream>>>(msgB, a2a, nsum);
    gemm_dma<5, 4, false, true, 6><<<256, 384, 0, stream>>>(
        fa, 160, nsum, 128, Wop, Wo_b, (const u16*)nullptr, msgA);

    readout<<<6250, 256, 0, stream>>>(msgA, ffn_w, ffn_b, out);
}